// Round 1
// baseline (77.725 us; speedup 1.0000x reference)
//
#include <hip/hip_runtime.h>
#include <math.h>

#define K_ 16
#define B_ 512
#define N_ 4096
#define V_ 32
#define TPB 256
#define CH (N_ / TPB)          // 16 elements per thread chunk
#define EPS_ 1e-13f

__global__ __launch_bounds__(TPB) void beran_kernel(
    const int* __restrict__ c_in, const float* __restrict__ delta_in,
    const float* __restrict__ c_p, const float* __restrict__ bandwidth,
    float* __restrict__ out) {
  __shared__ float p2[K_][V_];     // 2 * softmax probs
  __shared__ float wbuf[N_];       // raw weights, later surv values
  __shared__ float sumsq[K_];
  __shared__ float wscan[TPB / 64];
  __shared__ float s_base;

  const int b = blockIdx.x;
  const int t = threadIdx.x;
  const int lane = t & 63;
  const int wid = t >> 6;

  // ---- Phase 1: per-k softmax over V=32; store 2*p and sum(p^2) ----
  {
    const int k = t >> 4;          // 16 threads per concept k
    const int sub = t & 15;
    const int v0 = sub * 2;
    const float* cp = c_p + ((size_t)k * B_ + b) * V_;
    float x0 = cp[v0], x1 = cp[v0 + 1];
    float m = fmaxf(x0, x1);
#pragma unroll
    for (int d = 1; d < 16; d <<= 1) m = fmaxf(m, __shfl_xor(m, d, 64));
    float e0 = expf(x0 - m), e1 = expf(x1 - m);
    float sum = e0 + e1;
#pragma unroll
    for (int d = 1; d < 16; d <<= 1) sum += __shfl_xor(sum, d, 64);
    float inv = 1.0f / sum;
    float p0 = e0 * inv, p1 = e1 * inv;
    p2[k][v0] = 2.0f * p0;
    p2[k][v0 + 1] = 2.0f * p1;
    float ss = p0 * p0 + p1 * p1;
#pragma unroll
    for (int d = 1; d < 16; d <<= 1) ss += __shfl_xor(ss, d, 64);
    if (sub == 0) sumsq[k] = ss;
  }
  __syncthreads();
  if (t == 0) {
    float bs = 0.f;
#pragma unroll
    for (int k = 0; k < K_; k++) bs += sumsq[k];
    s_base = bs + (float)K_;       // sum_k (sum_sq + 1)
  }
  __syncthreads();
  const float base = s_base;
  float bw = bandwidth[0];
  bw = fminf(fmaxf(bw, 0.1f), 10.0f);
  const float invbw = 1.0f / bw;

  // ---- Phase 2: raw kernel weights w[n] = exp(-metric/bw) ----
  const int4* crow = (const int4*)c_in;   // row n = 16 ints = 4x int4
  for (int n = t; n < N_; n += TPB) {
    int4 a = crow[n * 4 + 0];
    int4 bb = crow[n * 4 + 1];
    int4 cc = crow[n * 4 + 2];
    int4 dd = crow[n * 4 + 3];
    float g = p2[0][a.x] + p2[1][a.y] + p2[2][a.z] + p2[3][a.w]
            + p2[4][bb.x] + p2[5][bb.y] + p2[6][bb.z] + p2[7][bb.w]
            + p2[8][cc.x] + p2[9][cc.y] + p2[10][cc.z] + p2[11][cc.w]
            + p2[12][dd.x] + p2[13][dd.y] + p2[14][dd.z] + p2[15][dd.w];
    wbuf[n] = expf(-(base - g) * invbw);
  }
  __syncthreads();

  // ---- Phase 3A: block scan of w; per-element xi; y = delta*xi in regs ----
  const int start = t * CH;
  float lv[CH];
  float tot = 0.f;
#pragma unroll
  for (int i = 0; i < CH; i++) { lv[i] = wbuf[start + i]; tot += lv[i]; }
  float inc = tot;
#pragma unroll
  for (int d = 1; d < 64; d <<= 1) {
    float u = __shfl_up(inc, d, 64);
    if (lane >= d) inc += u;
  }
  if (lane == 63) wscan[wid] = inc;
  __syncthreads();
  float s = 0.f, woff = 0.f;
#pragma unroll
  for (int j = 0; j < TPB / 64; j++) {
    float v = wscan[j];
    s += v;
    if (j < wid) woff += v;
  }
  const float inv_s = (s < EPS_) ? 0.f : 1.0f / s;
  float rawp = woff + (inc - tot);       // raw exclusive prefix

  // load own delta chunk (coalesced float4)
  const float4* dl4 = (const float4*)delta_in;
  float dl[CH];
#pragma unroll
  for (int j = 0; j < CH / 4; j++) {
    float4 d4 = dl4[t * (CH / 4) + j];
    dl[j * 4 + 0] = d4.x; dl[j * 4 + 1] = d4.y;
    dl[j * 4 + 2] = d4.z; dl[j * 4 + 3] = d4.w;
  }
  const float thr = 1.001e-5f;           // isclose: atol + rtol*|1.0|
#pragma unroll
  for (int i = 0; i < CH; i++) {
    float sh = rawp * inv_s;             // shifted (exclusive, normalized)
    rawp += lv[i];
    float wc = rawp * inv_s;             // w_cumsum (inclusive, normalized)
    float y = 0.f;
    bool bad = (fabsf(sh - 1.f) <= thr) || (fabsf(wc - 1.f) <= thr);
    if (dl[i] != 0.f && !bad)
      y = dl[i] * (logf(1.f - sh) - logf(1.f - wc));
    lv[i] = y;                           // reuse register array for y
  }
  __syncthreads();                       // wscan about to be reused

  // ---- Phase 3B: block scan of y -> hazards -> surv into wbuf ----
  float tot2 = 0.f;
#pragma unroll
  for (int i = 0; i < CH; i++) tot2 += lv[i];
  float inc2 = tot2;
#pragma unroll
  for (int d = 1; d < 64; d <<= 1) {
    float u = __shfl_up(inc2, d, 64);
    if (lane >= d) inc2 += u;
  }
  if (lane == 63) wscan[wid] = inc2;
  __syncthreads();
  float hoff = 0.f;
#pragma unroll
  for (int j = 0; j < TPB / 64; j++) if (j < wid) hoff += wscan[j];
  float h = hoff + (inc2 - tot2);        // exclusive hazard prefix
#pragma unroll
  for (int i = 0; i < CH; i++) {
    h += lv[i];
    wbuf[start + i] = expf(-h);          // surv_func
  }
  __syncthreads();

  // ---- Phase 4: outputs (coalesced) ----
  const float s2 = 1.0f - wbuf[N_ - 1];  // telescoped sum of surv_steps
  const float inv2 = (s2 < EPS_) ? 0.f : 1.0f / s2;
  float* out_s = out + (size_t)b * N_;
  float* out_t = out + (size_t)B_ * N_ + (size_t)b * N_;
  for (int n = t; n < N_; n += TPB) {
    float sv = wbuf[n];
    float pv = (n == 0) ? 1.0f : wbuf[n - 1];
    out_s[n] = sv;
    out_t[n] = (pv - sv) * inv2;
  }
}

extern "C" void kernel_launch(void* const* d_in, const int* in_sizes, int n_in,
                              void* d_out, int out_size, void* d_ws, size_t ws_size,
                              hipStream_t stream) {
  const int* c_in = (const int*)d_in[0];
  const float* delta_in = (const float*)d_in[1];
  const float* c_p = (const float*)d_in[2];
  const float* bandwidth = (const float*)d_in[3];
  float* outp = (float*)d_out;
  hipLaunchKernelGGL(beran_kernel, dim3(B_), dim3(TPB), 0, stream,
                     c_in, delta_in, c_p, bandwidth, outp);
}